// Round 1
// baseline (127.211 us; speedup 1.0000x reference)
//
#include <hip/hip_runtime.h>
#include <math.h>

// Problem constants
#define BN 16
#define H  480
#define W  640
#define HW (H * W)                 // 307200
#define QUADS_PER_IMG (HW / 4)     // 76800
#define TOTAL_QUADS (BN * QUADS_PER_IMG) // 1,228,800
#define INV_N (1.0f / (float)(BN * HW))

__global__ __launch_bounds__(256) void cheirality_kernel(
    const float* __restrict__ pose,       // (16,6)
    const float* __restrict__ grad,       // (16,2,480,640)
    const float* __restrict__ nf,         // (16,2,480,640)
    float* __restrict__ out)              // scalar
{
    __shared__ float sp[BN * 6];
    if (threadIdx.x < BN * 6) sp[threadIdx.x] = pose[threadIdx.x];
    __syncthreads();

    float local = 0.0f;

    const int stride = gridDim.x * blockDim.x;
    for (int q = blockIdx.x * blockDim.x + threadIdx.x; q < TOTAL_QUADS; q += stride) {
        const int b = q / QUADS_PER_IMG;
        const int r = q - b * QUADS_PER_IMG;
        const int p = r << 2;              // pixel index within image, multiple of 4
        const int row = p / W;             // y
        const int col = p - row * W;       // x of first pixel in quad

        const float fy  = (float)row;
        const float fy2p1 = fy * fy + 1.0f;

        const size_t base = (size_t)b * (2 * HW) + p;
        const float4 g0 = *(const float4*)(grad + base);
        const float4 g1 = *(const float4*)(grad + base + HW);
        const float4 n0 = *(const float4*)(nf   + base);
        const float4 n1 = *(const float4*)(nf   + base + HW);

        const float V0 = sp[b * 6 + 0];
        const float V1 = sp[b * 6 + 1];
        const float V2 = sp[b * 6 + 2];
        const float W0 = sp[b * 6 + 3];
        const float W1 = sp[b * 6 + 4];
        const float W2 = sp[b * 6 + 5];

        const float g0v[4] = {g0.x, g0.y, g0.z, g0.w};
        const float g1v[4] = {g1.x, g1.y, g1.z, g1.w};
        const float n0v[4] = {n0.x, n0.y, n0.z, n0.w};
        const float n1v[4] = {n1.x, n1.y, n1.z, n1.w};

        #pragma unroll
        for (int i = 0; i < 4; ++i) {
            const float fx = (float)(col + i);
            // AV components
            const float AV0 = fmaf(fx, V2, -V0);
            const float AV1 = fmaf(fy, V2, -V1);
            // BW components
            const float xy = fx * fy;
            const float BW0 = fmaf(xy, W0, fmaf(-(fx * fx + 1.0f), W1, fy * W2));
            const float BW1 = fmaf(fy2p1, W0, fmaf(-xy, W1, -fx * W2));

            const float s1 = fmaf(g0v[i], AV0, g1v[i] * AV1);
            const float s3 = fmaf(g0v[i], BW0, g1v[i] * BW1);
            const float rho = s1 * ((n0v[i] + n1v[i]) - s3);

            const float z = -rho;
            // exact GELU: 0.5*z*(1+erf(z/sqrt(2)))
            const float g = 0.5f * z * (1.0f + erff(z * 0.70710678118654752f));
            local += g;
        }
    }

    // wave (64-lane) reduction
    #pragma unroll
    for (int off = 32; off > 0; off >>= 1)
        local += __shfl_down(local, off, 64);

    __shared__ float waveSums[4];   // 256 threads / 64
    const int lane = threadIdx.x & 63;
    const int wid  = threadIdx.x >> 6;
    if (lane == 0) waveSums[wid] = local;
    __syncthreads();

    if (threadIdx.x == 0) {
        const float s = waveSums[0] + waveSums[1] + waveSums[2] + waveSums[3];
        atomicAdd(out, s * INV_N);
    }
}

extern "C" void kernel_launch(void* const* d_in, const int* in_sizes, int n_in,
                              void* d_out, int out_size, void* d_ws, size_t ws_size,
                              hipStream_t stream) {
    const float* pose = (const float*)d_in[0];
    const float* grad = (const float*)d_in[1];
    const float* nf   = (const float*)d_in[2];
    float* out = (float*)d_out;

    hipMemsetAsync(out, 0, sizeof(float), stream);

    // 2400 blocks x 256 threads: each thread processes exactly 2 quads.
    const int blocks = 2400;
    cheirality_kernel<<<blocks, 256, 0, stream>>>(pose, grad, nf, out);
}

// Round 2
// 104.301 us; speedup vs baseline: 1.2197x; 1.2197x over previous
//
#include <hip/hip_runtime.h>
#include <math.h>

// Problem constants
#define BN 16
#define H  480
#define W  640
#define HW (H * W)                   // 307200
#define QUADS_PER_IMG (HW / 4)       // 76800
#define TOTAL_QUADS (BN * QUADS_PER_IMG) // 1,228,800
#define INV_N (1.0f / (float)(BN * HW))

#define THREADS 256
#define BLOCKS  1200
#define ITERS   4
// BLOCKS*THREADS = 307200 threads; *ITERS = 1,228,800 = TOTAL_QUADS exactly.
// Iteration stride (307200 quads) == 4 whole images -> b advances by 4 per
// iter while (x,y) stays constant per thread.

__global__ __launch_bounds__(THREADS) void cheirality_main(
    const float* __restrict__ pose,     // (16,6)
    const float* __restrict__ grad,     // (16,2,480,640)
    const float* __restrict__ nf,       // (16,2,480,640)
    float* __restrict__ partial)        // (BLOCKS,)
{
    __shared__ float sp[BN * 6];
    if (threadIdx.x < BN * 6) sp[threadIdx.x] = pose[threadIdx.x];
    __syncthreads();

    const int tid0 = blockIdx.x * THREADS + threadIdx.x;   // 0..307199
    const int b0   = tid0 / QUADS_PER_IMG;                 // 0..3
    const int r    = tid0 - b0 * QUADS_PER_IMG;
    const int p    = r << 2;                               // pixel idx in image
    const int row  = p / W;
    const int col  = p - row * W;

    const float fy    = (float)row;
    const float fy2p1 = fy * fy + 1.0f;
    float fxv[4], xyv[4], x2p1[4];
    #pragma unroll
    for (int i = 0; i < 4; ++i) {
        const float fx = (float)(col + i);
        fxv[i]  = fx;
        xyv[i]  = fx * fy;
        x2p1[i] = fx * fx + 1.0f;
    }

    float local = 0.0f;

    // prefetch iteration 0
    int b = b0;
    size_t base = (size_t)b * (2 * HW) + p;
    float4 g0 = *(const float4*)(grad + base);
    float4 g1 = *(const float4*)(grad + base + HW);
    float4 n0 = *(const float4*)(nf   + base);
    float4 n1 = *(const float4*)(nf   + base + HW);

    #pragma unroll
    for (int it = 0; it < ITERS; ++it) {
        const float4 cg0 = g0, cg1 = g1, cn0 = n0, cn1 = n1;
        const int cb = b;
        if (it + 1 < ITERS) {           // issue next iter's loads before compute
            b += 4;
            base = (size_t)b * (2 * HW) + p;
            g0 = *(const float4*)(grad + base);
            g1 = *(const float4*)(grad + base + HW);
            n0 = *(const float4*)(nf   + base);
            n1 = *(const float4*)(nf   + base + HW);
        }

        const float V0 = sp[cb * 6 + 0];
        const float V1 = sp[cb * 6 + 1];
        const float V2 = sp[cb * 6 + 2];
        const float W0 = sp[cb * 6 + 3];
        const float W1 = sp[cb * 6 + 4];
        const float W2 = sp[cb * 6 + 5];

        const float AV1 = fmaf(fy, V2, -V1);   // shared by the 4 pixels

        const float g0a[4] = {cg0.x, cg0.y, cg0.z, cg0.w};
        const float g1a[4] = {cg1.x, cg1.y, cg1.z, cg1.w};
        const float n0a[4] = {cn0.x, cn0.y, cn0.z, cn0.w};
        const float n1a[4] = {cn1.x, cn1.y, cn1.z, cn1.w};

        #pragma unroll
        for (int i = 0; i < 4; ++i) {
            const float AV0 = fmaf(fxv[i], V2, -V0);
            const float BW0 = fmaf(xyv[i], W0, fmaf(-x2p1[i], W1, fy * W2));
            const float BW1 = fmaf(fy2p1, W0, fmaf(-xyv[i], W1, -fxv[i] * W2));

            const float s1  = fmaf(g0a[i], AV0, g1a[i] * AV1);
            const float s3  = fmaf(g0a[i], BW0, g1a[i] * BW1);
            const float rho = s1 * ((n0a[i] + n1a[i]) - s3);

            const float z = -rho;
            local += 0.5f * z * (1.0f + erff(z * 0.70710678118654752f));
        }
    }

    // wave (64-lane) reduction
    #pragma unroll
    for (int off = 32; off > 0; off >>= 1)
        local += __shfl_down(local, off, 64);

    __shared__ float waveSums[THREADS / 64];
    const int lane = threadIdx.x & 63;
    const int wid  = threadIdx.x >> 6;
    if (lane == 0) waveSums[wid] = local;
    __syncthreads();

    if (threadIdx.x == 0)
        partial[blockIdx.x] = waveSums[0] + waveSums[1] + waveSums[2] + waveSums[3];
}

__global__ __launch_bounds__(256) void cheirality_reduce(
    const float* __restrict__ partial, float* __restrict__ out)
{
    float v = 0.0f;
    for (int i = threadIdx.x; i < BLOCKS; i += 256)
        v += partial[i];

    #pragma unroll
    for (int off = 32; off > 0; off >>= 1)
        v += __shfl_down(v, off, 64);

    __shared__ float waveSums[4];
    const int lane = threadIdx.x & 63;
    const int wid  = threadIdx.x >> 6;
    if (lane == 0) waveSums[wid] = v;
    __syncthreads();

    if (threadIdx.x == 0)
        out[0] = (waveSums[0] + waveSums[1] + waveSums[2] + waveSums[3]) * INV_N;
}

extern "C" void kernel_launch(void* const* d_in, const int* in_sizes, int n_in,
                              void* d_out, int out_size, void* d_ws, size_t ws_size,
                              hipStream_t stream) {
    const float* pose = (const float*)d_in[0];
    const float* grad = (const float*)d_in[1];
    const float* nf   = (const float*)d_in[2];
    float* out     = (float*)d_out;
    float* partial = (float*)d_ws;   // BLOCKS floats of scratch

    cheirality_main<<<BLOCKS, THREADS, 0, stream>>>(pose, grad, nf, partial);
    cheirality_reduce<<<1, 256, 0, stream>>>(partial, out);
}

// Round 3
// 104.234 us; speedup vs baseline: 1.2204x; 1.0006x over previous
//
#include <hip/hip_runtime.h>
#include <math.h>

// Problem constants
#define BN 16
#define H  480
#define W  640
#define HW (H * W)                   // 307200
#define QUADS_PER_IMG (HW / 4)       // 76800
#define TOTAL_QUADS (BN * QUADS_PER_IMG) // 1,228,800
#define INV_N (1.0f / (float)(BN * HW))

#define THREADS 256
#define BLOCKS  2400
#define ITERS   2
// BLOCKS*THREADS = 614400 threads; *ITERS = 1,228,800 = TOTAL_QUADS exactly.
// Iteration stride (614400 quads) == 8 whole images -> b advances by 8 per
// iter while (x,y) stays constant per thread.

__device__ __forceinline__ void accum_quad(
    float& local,
    const float4& g0, const float4& g1, const float4& n0, const float4& n1,
    const float* __restrict__ sp6,                  // pose[b]*6 in LDS
    const float* fxv, const float* xyv, const float* x2p1,
    float fy, float fy2p1)
{
    const float V0 = sp6[0], V1 = sp6[1], V2 = sp6[2];
    const float W0 = sp6[3], W1 = sp6[4], W2 = sp6[5];

    const float AV1 = fmaf(fy, V2, -V1);            // shared by the 4 pixels

    const float g0a[4] = {g0.x, g0.y, g0.z, g0.w};
    const float g1a[4] = {g1.x, g1.y, g1.z, g1.w};
    const float n0a[4] = {n0.x, n0.y, n0.z, n0.w};
    const float n1a[4] = {n1.x, n1.y, n1.z, n1.w};

    #pragma unroll
    for (int i = 0; i < 4; ++i) {
        const float AV0 = fmaf(fxv[i], V2, -V0);
        const float BW0 = fmaf(xyv[i], W0, fmaf(-x2p1[i], W1, fy * W2));
        const float BW1 = fmaf(fy2p1, W0, fmaf(-xyv[i], W1, -fxv[i] * W2));

        const float s1  = fmaf(g0a[i], AV0, g1a[i] * AV1);
        const float s3  = fmaf(g0a[i], BW0, g1a[i] * BW1);
        const float rho = s1 * ((n0a[i] + n1a[i]) - s3);

        // GELU(z), z = -rho, sigmoid approximation:
        //   gelu(z) ~= z * sigmoid(1.702 z) = -rho / (1 + exp(1.702*rho))
        // exp->inf => rcp->0 => term->0 (matches exact tail); exp->0 => term=z.
        const float e = __expf(1.702f * rho);
        local += (-rho) * __builtin_amdgcn_rcpf(1.0f + e);
    }
}

__global__ __launch_bounds__(THREADS) void cheirality_main(
    const float* __restrict__ pose,     // (16,6)
    const float* __restrict__ grad,     // (16,2,480,640)
    const float* __restrict__ nf,       // (16,2,480,640)
    float* __restrict__ partial)        // (BLOCKS,)
{
    __shared__ float sp[BN * 6];
    if (threadIdx.x < BN * 6) sp[threadIdx.x] = pose[threadIdx.x];
    __syncthreads();

    const int tid0 = blockIdx.x * THREADS + threadIdx.x;   // 0..614399
    const int b0   = tid0 / QUADS_PER_IMG;                 // 0..7
    const int r    = tid0 - b0 * QUADS_PER_IMG;
    const int p    = r << 2;                               // pixel idx in image
    const int row  = p / W;
    const int col  = p - row * W;

    const float fy    = (float)row;
    const float fy2p1 = fy * fy + 1.0f;
    float fxv[4], xyv[4], x2p1[4];
    #pragma unroll
    for (int i = 0; i < 4; ++i) {
        const float fx = (float)(col + i);
        fxv[i]  = fx;
        xyv[i]  = fx * fy;
        x2p1[i] = fx * fx + 1.0f;
    }

    // Issue ALL 8 loads up front (2 iterations x 4 streams) for max MLP.
    const size_t base0 = (size_t)b0 * (2 * HW) + p;
    const size_t base1 = base0 + (size_t)8 * (2 * HW);
    const float4 Ag0 = *(const float4*)(grad + base0);
    const float4 Ag1 = *(const float4*)(grad + base0 + HW);
    const float4 An0 = *(const float4*)(nf   + base0);
    const float4 An1 = *(const float4*)(nf   + base0 + HW);
    const float4 Bg0 = *(const float4*)(grad + base1);
    const float4 Bg1 = *(const float4*)(grad + base1 + HW);
    const float4 Bn0 = *(const float4*)(nf   + base1);
    const float4 Bn1 = *(const float4*)(nf   + base1 + HW);

    float local = 0.0f;
    accum_quad(local, Ag0, Ag1, An0, An1, sp + b0 * 6,       fxv, xyv, x2p1, fy, fy2p1);
    accum_quad(local, Bg0, Bg1, Bn0, Bn1, sp + (b0 + 8) * 6, fxv, xyv, x2p1, fy, fy2p1);

    // wave (64-lane) reduction
    #pragma unroll
    for (int off = 32; off > 0; off >>= 1)
        local += __shfl_down(local, off, 64);

    __shared__ float waveSums[THREADS / 64];
    const int lane = threadIdx.x & 63;
    const int wid  = threadIdx.x >> 6;
    if (lane == 0) waveSums[wid] = local;
    __syncthreads();

    if (threadIdx.x == 0)
        partial[blockIdx.x] = waveSums[0] + waveSums[1] + waveSums[2] + waveSums[3];
}

__global__ __launch_bounds__(256) void cheirality_reduce(
    const float* __restrict__ partial, float* __restrict__ out)
{
    float v = 0.0f;
    for (int i = threadIdx.x; i < BLOCKS; i += 256)
        v += partial[i];

    #pragma unroll
    for (int off = 32; off > 0; off >>= 1)
        v += __shfl_down(v, off, 64);

    __shared__ float waveSums[4];
    const int lane = threadIdx.x & 63;
    const int wid  = threadIdx.x >> 6;
    if (lane == 0) waveSums[wid] = v;
    __syncthreads();

    if (threadIdx.x == 0)
        out[0] = (waveSums[0] + waveSums[1] + waveSums[2] + waveSums[3]) * INV_N;
}

extern "C" void kernel_launch(void* const* d_in, const int* in_sizes, int n_in,
                              void* d_out, int out_size, void* d_ws, size_t ws_size,
                              hipStream_t stream) {
    const float* pose = (const float*)d_in[0];
    const float* grad = (const float*)d_in[1];
    const float* nf   = (const float*)d_in[2];
    float* out     = (float*)d_out;
    float* partial = (float*)d_ws;   // BLOCKS floats of scratch

    cheirality_main<<<BLOCKS, THREADS, 0, stream>>>(pose, grad, nf, partial);
    cheirality_reduce<<<1, 256, 0, stream>>>(partial, out);
}